// Round 5
// baseline (483.638 us; speedup 1.0000x reference)
//
#include <hip/hip_runtime.h>
#include <math.h>

#define NROWS 500000
#define DIM 256
#define YDIM 50
#define NLAB 1000

#define XTILE 32
#define NTX (NROWS / XTILE)        // 15625 exact
#define XBLOCKS 256
#define ASTRIDE 264                // ushorts per A-tile row (pad vs 256)

#define YTROWS 128
#define NTY ((NROWS + YTROWS - 1) / YTROWS)   // 3907
#define YBLOCKS 256

typedef __attribute__((ext_vector_type(8))) short frag_ab;
typedef __attribute__((ext_vector_type(4))) float frag_cd;

__device__ __forceinline__ float b2f(unsigned short u) {
    return __uint_as_float(((unsigned)u) << 16);
}
__device__ __forceinline__ unsigned short f2b(float f) {   // RNE f32->bf16
    unsigned u = __float_as_uint(f);
    return (unsigned short)((u + 0x7fffu + ((u >> 16) & 1u)) >> 16);
}

// ---------- label histogram (counts for denom) + zero the output ----------
__global__ __launch_bounds__(256) void k_hist(const int* __restrict__ labels,
                                              int* __restrict__ hist,
                                              float* __restrict__ out) {
    __shared__ int lh[NLAB];
    for (int i = threadIdx.x; i < NLAB; i += 256) lh[i] = 0;
    if (blockIdx.x == 0 && threadIdx.x == 0) out[0] = 0.0f;
    __syncthreads();
    for (int i = blockIdx.x * 256 + threadIdx.x; i < NROWS; i += gridDim.x * 256)
        atomicAdd(&lh[labels[i]], 1);
    __syncthreads();
    for (int i = threadIdx.x; i < NLAB; i += 256) {
        int v = lh[i];
        if (v) atomicAdd(&hist[i], v);
    }
}

// ---------- per-wave serialized z-accumulate into LDS bf16 ----------
// C/D layout (m89-verified): lane holds D[16*mh + (lane>>4)*4 + tt][16*jt + (lane&15)]
__device__ __forceinline__ void acc_write(unsigned short* accz, const frag_cd& c,
                                          int lane, int mh, int jt, int lblreg) {
    const int q = lane >> 4;
    const int j = 16 * jt + (lane & 15);
    #pragma unroll
    for (int qq = 0; qq < 4; ++qq) {
        #pragma unroll
        for (int tt = 0; tt < 4; ++tt) {
            const int rl = 16 * mh + 4 * qq + tt;
            const int lbl = __shfl(lblreg, rl & 31);
            if (q == qq && j < YDIM) {
                const int a = lbl * YDIM + j;
                accz[a] = f2b(b2f(accz[a]) + c[tt]);   // one row at a time: race-free
            }
        }
    }
}

__device__ __forceinline__ void process_tile(
    int t, int pft,
    float4& r0, float4& r1, float4& r2, float4& r3,
    const float* __restrict__ x, const int* __restrict__ labels,
    const float4& wv, float b1v,
    unsigned short* sA, const uint4* sB, unsigned short* accz,
    int lane, int wib, int mh, int jt)
{
    const int lblreg = labels[t * XTILE + (lane & 31)];

    // gate: dot(row, w1) via butterfly, then sigmoid
    float p0 = r0.x*wv.x + r0.y*wv.y + r0.z*wv.z + r0.w*wv.w;
    float p1 = r1.x*wv.x + r1.y*wv.y + r1.z*wv.z + r1.w*wv.w;
    float p2 = r2.x*wv.x + r2.y*wv.y + r2.z*wv.z + r2.w*wv.w;
    float p3 = r3.x*wv.x + r3.y*wv.y + r3.z*wv.z + r3.w*wv.w;
    #pragma unroll
    for (int off = 32; off > 0; off >>= 1) {
        p0 += __shfl_xor(p0, off); p1 += __shfl_xor(p1, off);
        p2 += __shfl_xor(p2, off); p3 += __shfl_xor(p3, off);
    }
    const float g0 = 1.0f / (1.0f + __expf(-(p0 + b1v)));
    const float g1 = 1.0f / (1.0f + __expf(-(p1 + b1v)));
    const float g2 = 1.0f / (1.0f + __expf(-(p2 + b1v)));
    const float g3 = 1.0f / (1.0f + __expf(-(p3 + b1v)));

    // write A = g*x as bf16 rows (previous tile fully consumed at last barrier)
    {
        const int row = 4 * wib;
        unsigned ua = (unsigned)f2b(r0.x*g0) | ((unsigned)f2b(r0.y*g0) << 16);
        unsigned ub = (unsigned)f2b(r0.z*g0) | ((unsigned)f2b(r0.w*g0) << 16);
        *reinterpret_cast<uint2*>(&sA[(row + 0) * ASTRIDE + lane * 4]) = make_uint2(ua, ub);
        ua = (unsigned)f2b(r1.x*g1) | ((unsigned)f2b(r1.y*g1) << 16);
        ub = (unsigned)f2b(r1.z*g1) | ((unsigned)f2b(r1.w*g1) << 16);
        *reinterpret_cast<uint2*>(&sA[(row + 1) * ASTRIDE + lane * 4]) = make_uint2(ua, ub);
        ua = (unsigned)f2b(r2.x*g2) | ((unsigned)f2b(r2.y*g2) << 16);
        ub = (unsigned)f2b(r2.z*g2) | ((unsigned)f2b(r2.w*g2) << 16);
        *reinterpret_cast<uint2*>(&sA[(row + 2) * ASTRIDE + lane * 4]) = make_uint2(ua, ub);
        ua = (unsigned)f2b(r3.x*g3) | ((unsigned)f2b(r3.y*g3) << 16);
        ub = (unsigned)f2b(r3.z*g3) | ((unsigned)f2b(r3.w*g3) << 16);
        *reinterpret_cast<uint2*>(&sA[(row + 3) * ASTRIDE + lane * 4]) = make_uint2(ua, ub);
    }
    // prefetch rows for tile 'pft' into the freed regs (in flight across MFMA+acc)
    if (pft < NTX) {
        const float4* Xp = reinterpret_cast<const float4*>(x)
                           + ((size_t)pft * XTILE + 4 * wib) * 64 + lane;
        r0 = Xp[0]; r1 = Xp[64]; r2 = Xp[128]; r3 = Xp[192];
    }
    __syncthreads();   // A-tile ready

    frag_cd c = {0.f, 0.f, 0.f, 0.f};
    #pragma unroll
    for (int s = 0; s < 8; ++s) {
        frag_ab a = *reinterpret_cast<const frag_ab*>(
            &sA[(16 * mh + (lane & 15)) * ASTRIDE + 32 * s + (lane >> 4) * 8]);
        frag_ab b = *reinterpret_cast<const frag_ab*>(&sB[(s * 4 + jt) * 64 + lane]);
        c = __builtin_amdgcn_mfma_f32_16x16x32_bf16(a, b, c, 0, 0, 0);
    }
    // two phases: row-half 0 waves, then row-half 1 waves (label collisions serialized)
    if (wib < 4) acc_write(accz, c, lane, mh, jt, lblreg);
    __syncthreads();
    if (wib >= 4) acc_write(accz, c, lane, mh, jt, lblreg);
    __syncthreads();
}

// ---------- sequential x stream: z = g*(x@w2), block-local bf16 label acc ----------
__global__ __launch_bounds__(512) void k_xstream(
    const float* __restrict__ x, const int* __restrict__ labels,
    const float* __restrict__ w1, const float* __restrict__ b1,
    const float* __restrict__ w2, unsigned short* __restrict__ zpart)
{
    __shared__ unsigned short sA[XTILE * ASTRIDE];   // 16,896 B
    __shared__ uint4 sB[32 * 64];                    // 32,768 B  (8 k-steps x 4 j-tiles)
    __shared__ unsigned short accz[NLAB * YDIM];     // 100,000 B

    const int tid = threadIdx.x, lane = tid & 63, wib = tid >> 6;
    const int bid = blockIdx.x;
    const int mh = wib >> 2, jt = wib & 3;

    for (int k = tid; k < NLAB * YDIM / 2; k += 512)
        reinterpret_cast<unsigned*>(accz)[k] = 0u;

    // build B fragments from w2 (k = d, n = j), bf16, zero-padded j>=50
    for (int fi = wib; fi < 32; fi += 8) {
        const int s = fi >> 2, jtt = fi & 3;
        unsigned u[4];
        #pragma unroll
        for (int i = 0; i < 4; ++i) {
            const int k0 = 32 * s + (lane >> 4) * 8 + 2 * i;
            const int n = 16 * jtt + (lane & 15);
            const float v0 = (n < YDIM) ? w2[k0 * YDIM + n] : 0.f;
            const float v1 = (n < YDIM) ? w2[(k0 + 1) * YDIM + n] : 0.f;
            u[i] = (unsigned)f2b(v0) | ((unsigned)f2b(v1) << 16);
        }
        sB[fi * 64 + lane] = make_uint4(u[0], u[1], u[2], u[3]);
    }
    const float4 wv = reinterpret_cast<const float4*>(w1)[lane];
    const float b1v = b1[0];
    __syncthreads();

    float4 ra0, ra1, ra2, ra3, rb0, rb1, rb2, rb3;
    {
        const float4* Xp = reinterpret_cast<const float4*>(x)
                           + ((size_t)bid * XTILE + 4 * wib) * 64 + lane;
        ra0 = Xp[0]; ra1 = Xp[64]; ra2 = Xp[128]; ra3 = Xp[192];
        const int tB = bid + XBLOCKS;
        if (tB < NTX) {
            const float4* Xq = reinterpret_cast<const float4*>(x)
                               + ((size_t)tB * XTILE + 4 * wib) * 64 + lane;
            rb0 = Xq[0]; rb1 = Xq[64]; rb2 = Xq[128]; rb3 = Xq[192];
        }
    }
    for (int t = bid; t < NTX; t += 2 * XBLOCKS) {
        process_tile(t, t + 2 * XBLOCKS, ra0, ra1, ra2, ra3,
                     x, labels, wv, b1v, sA, sB, accz, lane, wib, mh, jt);
        if (t + XBLOCKS < NTX)
            process_tile(t + XBLOCKS, t + 3 * XBLOCKS, rb0, rb1, rb2, rb3,
                         x, labels, wv, b1v, sA, sB, accz, lane, wib, mh, jt);
    }
    __syncthreads();
    unsigned short* zp = zpart + (size_t)bid * (NLAB * YDIM);
    for (int k = tid; k < NLAB * YDIM; k += 512) zp[k] = accz[k];
}

// ---------- sequential y stream: block-local bf16 label acc ----------
__global__ __launch_bounds__(512) void k_ystream(
    const float* __restrict__ y, const int* __restrict__ labels,
    unsigned short* __restrict__ ypart)
{
    __shared__ unsigned short accy[NLAB * YDIM];   // 100,000 B
    __shared__ float stg[YTROWS * YDIM];           // 25,600 B
    __shared__ int slab[YTROWS];

    const int tid = threadIdx.x, lane = tid & 63, wib = tid >> 6;
    const int bid = blockIdx.x;

    for (int k = tid; k < NLAB * YDIM / 2; k += 512)
        reinterpret_cast<unsigned*>(accy)[k] = 0u;
    __syncthreads();

    for (int ty = bid; ty < NTY; ty += YBLOCKS) {
        const int rbase = ty * YTROWS;
        const int rows = min(YTROWS, NROWS - rbase);
        const int n = rows * YDIM;
        float v[13];
        #pragma unroll
        for (int i = 0; i < 13; ++i) {
            const int k = tid + i * 512;
            v[i] = (k < n) ? y[(size_t)rbase * YDIM + k] : 0.f;
        }
        if (tid < YTROWS) slab[tid] = (tid < rows) ? labels[rbase + tid] : 0;
        #pragma unroll
        for (int i = 0; i < 13; ++i) {
            const int k = tid + i * 512;
            if (k < YTROWS * YDIM) stg[k] = v[i];   // zero-padded tail: adds 0, harmless
        }
        __syncthreads();
        for (int p = 0; p < 8; ++p) {
            if (wib == p) {                          // one wave adds at a time: race-free
                for (int r = p * 16; r < p * 16 + 16; ++r) {
                    const int lbl = slab[r];
                    if (lane < YDIM) {
                        const int a = lbl * YDIM + lane;
                        accy[a] = f2b(b2f(accy[a]) + stg[r * YDIM + lane]);
                    }
                }
            }
            __syncthreads();
        }
    }
    unsigned short* yp = ypart + (size_t)bid * (NLAB * YDIM);
    for (int k = tid; k < NLAB * YDIM; k += 512) yp[k] = accy[k];
}

// ---------- reduce partials + double softmax + loss ----------
__global__ __launch_bounds__(256) void k_finalize(
    const unsigned short* __restrict__ zpart,
    const unsigned short* __restrict__ ypart,
    const int* __restrict__ hist,
    const float* __restrict__ b2, float* __restrict__ out)
{
    const int tid = threadIdx.x, lane = tid & 63, grp = tid >> 6;
    const int l = blockIdx.x * 4 + grp;            // 250 blocks * 4 = 1000
    const bool act = lane < YDIM;
    const int off = l * YDIM + lane;
    float zs = 0.f, ys = 0.f;
    #pragma unroll 4
    for (int b = 0; b < XBLOCKS; ++b) {
        if (act) {
            zs += b2f(zpart[(size_t)b * (NLAB * YDIM) + off]);
            ys += b2f(ypart[(size_t)b * (NLAB * YDIM) + off]);
        }
    }
    const float denom = fmaxf((float)hist[l], 1.0f);
    const float NEG = -3.402823466e38f;
    float logit = act ? (zs / denom + b2[lane]) : NEG;
    const float ymean = act ? (ys / denom) : 0.f;

    float m = logit;
    #pragma unroll
    for (int o = 32; o > 0; o >>= 1) m = fmaxf(m, __shfl_xor(m, o));
    float e = act ? __expf(logit - m) : 0.f;
    float s = e;
    #pragma unroll
    for (int o = 32; o > 0; o >>= 1) s += __shfl_xor(s, o);
    const float p = e / s;                 // prediction

    float pm = act ? p : NEG;              // faithful double softmax
    float m2 = pm;
    #pragma unroll
    for (int o = 32; o > 0; o >>= 1) m2 = fmaxf(m2, __shfl_xor(m2, o));
    float e2 = act ? __expf(p - m2) : 0.f;
    float s2 = e2;
    #pragma unroll
    for (int o = 32; o > 0; o >>= 1) s2 += __shfl_xor(s2, o);
    const float logp = p - m2 - __logf(s2);

    float contrib = act ? ymean * logp : 0.f;
    #pragma unroll
    for (int o = 32; o > 0; o >>= 1) contrib += __shfl_xor(contrib, o);
    if (lane == 0) atomicAdd(out, -contrib / (float)NLAB);
}

extern "C" void kernel_launch(void* const* d_in, const int* in_sizes, int n_in,
                              void* d_out, int out_size, void* d_ws, size_t ws_size,
                              hipStream_t stream) {
    const float* x      = (const float*)d_in[0];
    const int*   labels = (const int*)  d_in[1];
    const float* y      = (const float*)d_in[2];
    const float* w1     = (const float*)d_in[3];
    const float* b1     = (const float*)d_in[4];
    const float* w2     = (const float*)d_in[5];
    const float* b2     = (const float*)d_in[6];
    float* out = (float*)d_out;

    // ws: hist[1000] | zpart[256][1000*50] bf16 | ypart[256][1000*50] bf16  (~51.2 MB)
    int* hist = (int*)d_ws;
    unsigned short* zpart = (unsigned short*)((char*)d_ws + 4096);
    unsigned short* ypart = (unsigned short*)((char*)d_ws + 4096 +
                             (size_t)XBLOCKS * NLAB * YDIM * 2);

    hipMemsetAsync(hist, 0, NLAB * sizeof(int), stream);
    k_hist<<<256, 256, 0, stream>>>(labels, hist, out);
    k_xstream<<<XBLOCKS, 512, 0, stream>>>(x, labels, w1, b1, w2, zpart);
    k_ystream<<<YBLOCKS, 512, 0, stream>>>(y, labels, ypart);
    k_finalize<<<250, 256, 0, stream>>>(zpart, ypart, hist, b2, out);
}

// Round 6
// 300.184 us; speedup vs baseline: 1.6111x; 1.6111x over previous
//
#include <hip/hip_runtime.h>
#include <math.h>

#define NROWS 500000
#define DIM 256
#define YDIM 50
#define NLAB 1000

#define XT 64
#define NTX ((NROWS + XT - 1) / XT)      // 7813 (last tile: 32 valid rows)
#define XBLOCKS 256
#define ASTRIDE 264                      // bf16 elems per A row (padded)

#define YT 128
#define NTY ((NROWS + YT - 1) / YT)      // 3907
#define YBLOCKS 256

typedef __attribute__((ext_vector_type(8))) short frag_ab;
typedef __attribute__((ext_vector_type(4))) float frag_cd;

__device__ __forceinline__ float b2f(unsigned short u) {
    return __uint_as_float(((unsigned)u) << 16);
}
__device__ __forceinline__ unsigned short f2b(float f) {   // RNE f32->bf16
    unsigned u = __float_as_uint(f);
    return (unsigned short)((u + 0x7fffu + ((u >> 16) & 1u)) >> 16);
}
// LDS-only barrier: does NOT drain vmcnt -> global prefetches stay in flight.
__device__ __forceinline__ void bar_lds() {
    asm volatile("s_waitcnt lgkmcnt(0)\n\ts_barrier" ::: "memory");
}

// ============ x stream: z = g*(x@w2), owner-dedupe LDS accumulate ============
__global__ __launch_bounds__(1024, 4) void k_xstream(
    const float* __restrict__ x, const int* __restrict__ labels,
    const float* __restrict__ w1, const float* __restrict__ b1,
    const float* __restrict__ w2, unsigned short* __restrict__ zpart,
    float* __restrict__ out)
{
    __shared__ unsigned short sA[XT * ASTRIDE];      // 33,792 B
    __shared__ float zst[XT][52];                    // 13,312 B
    __shared__ unsigned short accz[NLAB * YDIM];     // 100,000 B
    __shared__ int owner[NLAB];                      //  4,000 B
    __shared__ int slab[2][XT];                      //    512 B
    __shared__ int ldrow[XT];                        //    256 B
    __shared__ int lflag[XT];                        //    256 B

    const int tid = threadIdx.x, lane = tid & 63, wib = tid >> 6;
    const int bid = blockIdx.x;
    const int mh = wib >> 2, jt = wib & 3;

    if (bid == 0 && tid == 0) out[0] = 0.0f;
    for (int k = tid; k < NLAB * YDIM / 2; k += 1024)
        reinterpret_cast<unsigned*>(accz)[k] = 0u;

    // B fragments (w2) held in registers: 8 k-steps for this wave's jt
    frag_ab bfr[8];
    {
        const int n = 16 * jt + (lane & 15);
        #pragma unroll
        for (int s = 0; s < 8; ++s) {
            const int k0 = 32 * s + (lane >> 4) * 8;
            #pragma unroll
            for (int i = 0; i < 8; ++i) {
                const float v = (n < YDIM) ? w2[(k0 + i) * YDIM + n] : 0.f;
                bfr[s][i] = (short)f2b(v);
            }
        }
    }
    const float4 wv = reinterpret_cast<const float4*>(w1)[lane];
    const float b1v = b1[0];
    __syncthreads();                                  // accz zeroed

    auto PREF = [&](int t, float4* r) {
        #pragma unroll
        for (int k = 0; k < 4; ++k) {
            const int rg = t * XT + 4 * wib + k;
            r[k] = (rg < NROWS)
                 ? reinterpret_cast<const float4*>(x)[(size_t)rg * 64 + lane]
                 : make_float4(0.f, 0.f, 0.f, 0.f);
        }
    };

    auto process = [&](int t, int pft, float4* r, int par) {
        // ---- pre-barrier: slab+owner, gates, A-write, prefetch ----
        if (tid < XT) {
            const int rg = t * XT + tid;
            const int lb = (rg < NROWS) ? labels[rg] : 0;
            slab[par][tid] = lb;
            owner[lb] = tid;           // last-writer-wins leader pick
        }
        float p[4], g[4];
        #pragma unroll
        for (int k = 0; k < 4; ++k)
            p[k] = r[k].x * wv.x + r[k].y * wv.y + r[k].z * wv.z + r[k].w * wv.w;
        #pragma unroll
        for (int off = 32; off > 0; off >>= 1) {
            #pragma unroll
            for (int k = 0; k < 4; ++k) p[k] += __shfl_xor(p[k], off);
        }
        #pragma unroll
        for (int k = 0; k < 4; ++k)
            g[k] = 1.0f / (1.0f + __expf(-(p[k] + b1v)));

        const int row = 4 * wib;
        #pragma unroll
        for (int k = 0; k < 4; ++k) {
            const unsigned ua = (unsigned)f2b(r[k].x * g[k]) |
                                ((unsigned)f2b(r[k].y * g[k]) << 16);
            const unsigned ub = (unsigned)f2b(r[k].z * g[k]) |
                                ((unsigned)f2b(r[k].w * g[k]) << 16);
            *reinterpret_cast<uint2*>(&sA[(row + k) * ASTRIDE + lane * 4]) =
                make_uint2(ua, ub);
        }
        PREF(pft, r);                  // next tile's loads: stay in flight
        bar_lds();                     // A + slab ready (no vmcnt drain!)

        // ---- MFMA ----
        frag_cd c = {0.f, 0.f, 0.f, 0.f};
        #pragma unroll
        for (int s = 0; s < 8; ++s) {
            frag_ab a = *reinterpret_cast<const frag_ab*>(
                &sA[(16 * mh + (lane & 15)) * ASTRIDE + 32 * s + (lane >> 4) * 8]);
            c = __builtin_amdgcn_mfma_f32_16x16x32_bf16(a, bfr[s], c, 0, 0, 0);
        }
        const int zr = 16 * mh + (lane >> 4) * 4;
        const int zc = 16 * jt + (lane & 15);
        if (zc < YDIM) {
            zst[zr + 0][zc] = c[0]; zst[zr + 1][zc] = c[1];
            zst[zr + 2][zc] = c[2]; zst[zr + 3][zc] = c[3];
        }
        bar_lds();                     // zstage + owner ready

        if (tid < XT) {
            const int l = owner[slab[par][tid]];
            ldrow[tid] = l;
            lflag[tid] = (l == tid);
        }
        bar_lds();                     // leaders known

        // ---- merge duplicate-label rows into leader rows (parallel, atomic) ----
        #pragma unroll
        for (int k = 0; k < 4; ++k) {
            const int r2 = wib + 16 * k;
            if (lane < YDIM && !lflag[r2])
                atomicAdd(&zst[ldrow[r2]][lane], zst[r2][lane]);
        }
        bar_lds();                     // merges done

        // ---- scatter: leaders only, unique (label,col) -> race-free RMW ----
        #pragma unroll
        for (int k = 0; k < 4; ++k) {
            const int r2 = wib + 16 * k;
            if (lane < YDIM && lflag[r2]) {
                const int a = slab[par][r2] * YDIM + lane;
                accz[a] = f2b(b2f(accz[a]) + zst[r2][lane]);
            }
        }
        // zst reuse protected by next tile's first bar_lds
    };

    float4 ra[4], rb[4];
    PREF(bid, ra);
    PREF(bid + XBLOCKS, rb);
    int par = 0;
    for (int t = bid; t < NTX; t += 2 * XBLOCKS) {
        process(t, t + 2 * XBLOCKS, ra, par); par ^= 1;
        if (t + XBLOCKS < NTX) {
            process(t + XBLOCKS, t + 3 * XBLOCKS, rb, par); par ^= 1;
        }
    }
    __syncthreads();
    unsigned short* zp = zpart + (size_t)bid * (NLAB * YDIM);
    for (int k = tid; k < NLAB * YDIM; k += 1024) zp[k] = accz[k];
}

// ============ y stream: owner-dedupe LDS accumulate + label counts ============
__global__ __launch_bounds__(1024, 4) void k_ystream(
    const float* __restrict__ y, const int* __restrict__ labels,
    unsigned short* __restrict__ ypart, int* __restrict__ gcnt)
{
    __shared__ unsigned short accy[NLAB * YDIM];   // 100,000 B
    __shared__ float yst[YT * YDIM];               //  25,600 B
    __shared__ int owner[NLAB];                    //   4,000 B
    __shared__ int slab[2][YT];                    //   1,024 B
    __shared__ int ldrow[YT];                      //     512 B
    __shared__ int lflag[YT];                      //     512 B
    __shared__ int cnt[NLAB];                      //   4,000 B

    const int tid = threadIdx.x, lane = tid & 63, wib = tid >> 6;
    const int bid = blockIdx.x;

    for (int k = tid; k < NLAB * YDIM / 2; k += 1024)
        reinterpret_cast<unsigned*>(accy)[k] = 0u;
    for (int k = tid; k < NLAB; k += 1024) cnt[k] = 0;
    __syncthreads();

    float v[7];
    int myl = -1;
    auto PREFY = [&](int t) {
        const size_t base = (size_t)t * YT * YDIM;
        const int n = (t < NTY) ? (min(YT, NROWS - t * YT) * YDIM) : 0;
        #pragma unroll
        for (int i = 0; i < 7; ++i) {
            const int k = tid + i * 1024;
            v[i] = (k < n) ? y[base + k] : 0.f;
        }
        if (tid < YT) {
            const int rg = t * YT + tid;
            myl = (t < NTY && rg < NROWS) ? labels[rg] : -1;
        }
    };

    PREFY(bid);
    int par = 0;
    for (int t = bid; t < NTY; t += YBLOCKS) {
        #pragma unroll
        for (int i = 0; i < 7; ++i) {
            const int k = tid + i * 1024;
            if (k < YT * YDIM) yst[k] = v[i];
        }
        if (tid < YT) {
            const bool valid = (myl >= 0);
            const int lb = valid ? myl : 0;
            slab[par][tid] = lb;
            owner[lb] = tid;
            if (valid) atomicAdd(&cnt[lb], 1);
        }
        PREFY(t + YBLOCKS);            // next tile loads in flight
        bar_lds();                     // stage + slab + owner ready

        if (tid < YT) {
            const int l = owner[slab[par][tid]];
            ldrow[tid] = l;
            lflag[tid] = (l == tid);
        }
        bar_lds();

        #pragma unroll
        for (int k = 0; k < 8; ++k) {
            const int r = wib + 16 * k;
            if (lane < YDIM && !lflag[r])
                atomicAdd(&yst[ldrow[r] * YDIM + lane], yst[r * YDIM + lane]);
        }
        bar_lds();

        #pragma unroll
        for (int k = 0; k < 8; ++k) {
            const int r = wib + 16 * k;
            if (lane < YDIM && lflag[r]) {
                const int a = slab[par][r] * YDIM + lane;
                accy[a] = f2b(b2f(accy[a]) + yst[r * YDIM + lane]);
            }
        }
        bar_lds();                     // yst free for next stage
        par ^= 1;
    }
    __syncthreads();
    unsigned short* yp = ypart + (size_t)bid * (NLAB * YDIM);
    for (int k = tid; k < NLAB * YDIM; k += 1024) yp[k] = accy[k];
    for (int k = tid; k < NLAB; k += 1024)
        if (cnt[k]) atomicAdd(&gcnt[k], cnt[k]);
}

// ============ reduce partials + double softmax + loss ============
__global__ __launch_bounds__(256) void k_finalize(
    const unsigned short* __restrict__ zpart,
    const unsigned short* __restrict__ ypart,
    const int* __restrict__ gcnt,
    const float* __restrict__ b2, float* __restrict__ out)
{
    const int tid = threadIdx.x, lane = tid & 63, grp = tid >> 6;
    const int l = blockIdx.x * 4 + grp;            // 250 blocks * 4 = 1000
    const bool act = lane < YDIM;
    const int off = l * YDIM + lane;
    float zs = 0.f, ys = 0.f;
    #pragma unroll 4
    for (int b = 0; b < XBLOCKS; ++b) {
        if (act) {
            zs += b2f(zpart[(size_t)b * (NLAB * YDIM) + off]);
            ys += b2f(ypart[(size_t)b * (NLAB * YDIM) + off]);
        }
    }
    const float denom = fmaxf((float)gcnt[l], 1.0f);
    const float NEG = -3.402823466e38f;
    float logit = act ? (zs / denom + b2[lane]) : NEG;
    const float ymean = act ? (ys / denom) : 0.f;

    float m = logit;
    #pragma unroll
    for (int o = 32; o > 0; o >>= 1) m = fmaxf(m, __shfl_xor(m, o));
    float e = act ? __expf(logit - m) : 0.f;
    float s = e;
    #pragma unroll
    for (int o = 32; o > 0; o >>= 1) s += __shfl_xor(s, o);
    const float p = e / s;                 // prediction

    float pm = act ? p : NEG;              // faithful double softmax
    float m2 = pm;
    #pragma unroll
    for (int o = 32; o > 0; o >>= 1) m2 = fmaxf(m2, __shfl_xor(m2, o));
    float e2 = act ? __expf(p - m2) : 0.f;
    float s2 = e2;
    #pragma unroll
    for (int o = 32; o > 0; o >>= 1) s2 += __shfl_xor(s2, o);
    const float logp = p - m2 - __logf(s2);

    float contrib = act ? ymean * logp : 0.f;
    #pragma unroll
    for (int o = 32; o > 0; o >>= 1) contrib += __shfl_xor(contrib, o);
    if (lane == 0) atomicAdd(out, -contrib / (float)NLAB);
}

extern "C" void kernel_launch(void* const* d_in, const int* in_sizes, int n_in,
                              void* d_out, int out_size, void* d_ws, size_t ws_size,
                              hipStream_t stream) {
    const float* x      = (const float*)d_in[0];
    const int*   labels = (const int*)  d_in[1];
    const float* y      = (const float*)d_in[2];
    const float* w1     = (const float*)d_in[3];
    const float* b1     = (const float*)d_in[4];
    const float* w2     = (const float*)d_in[5];
    const float* b2     = (const float*)d_in[6];
    float* out = (float*)d_out;

    // ws: gcnt[1024] ints | zpart[256][50000] bf16 | ypart[256][50000] bf16
    int* gcnt = (int*)d_ws;
    unsigned short* zpart = (unsigned short*)((char*)d_ws + 4096);
    unsigned short* ypart = (unsigned short*)((char*)d_ws + 4096 +
                             (size_t)XBLOCKS * NLAB * YDIM * 2);

    hipMemsetAsync(gcnt, 0, NLAB * sizeof(int), stream);
    k_xstream<<<XBLOCKS, 1024, 0, stream>>>(x, labels, w1, b1, w2, zpart, out);
    k_ystream<<<YBLOCKS, 1024, 0, stream>>>(y, labels, ypart, gcnt);
    k_finalize<<<250, 256, 0, stream>>>(zpart, ypart, gcnt, b2, out);
}

// Round 7
// 280.802 us; speedup vs baseline: 1.7223x; 1.0690x over previous
//
#include <hip/hip_runtime.h>
#include <math.h>

#define NROWS 500000
#define DIM 256
#define YDIM 50
#define NLAB 1000

#define XT 64
#define NTX ((NROWS + XT - 1) / XT)      // 7813 (last tile: 32 valid rows)
#define XBLOCKS 256
#define ASTRIDE 264                      // bf16 elems per A row (padded)

#define YT 128
#define NTY ((NROWS + YT - 1) / YT)      // 3907
#define YBLOCKS 256

typedef __attribute__((ext_vector_type(8))) short frag_ab;
typedef __attribute__((ext_vector_type(4))) float frag_cd;

__device__ __forceinline__ float b2f(unsigned short u) {
    return __uint_as_float(((unsigned)u) << 16);
}
__device__ __forceinline__ unsigned short f2b(float f) {   // RNE f32->bf16
    unsigned u = __float_as_uint(f);
    return (unsigned short)((u + 0x7fffu + ((u >> 16) & 1u)) >> 16);
}
// LDS-only barrier: does NOT drain vmcnt -> global prefetches stay in flight.
__device__ __forceinline__ void bar_lds() {
    asm volatile("s_waitcnt lgkmcnt(0)\n\ts_barrier" ::: "memory");
}

// ============ x stream: z = g*(x@w2); wave w owns labels (lbl&15)==w ============
__global__ __launch_bounds__(1024, 4) void k_xstream(
    const float* __restrict__ x, const int* __restrict__ labels,
    const float* __restrict__ w1, const float* __restrict__ b1,
    const float* __restrict__ w2, unsigned short* __restrict__ zpart,
    float* __restrict__ out)
{
    __shared__ unsigned short sA[XT * ASTRIDE];      // 33,792 B
    __shared__ float zst[XT][52];                    // 13,312 B
    __shared__ unsigned short accz[NLAB * YDIM];     // 100,000 B
    __shared__ int slab[XT];                         //    256 B

    const int tid = threadIdx.x, lane = tid & 63, wib = tid >> 6;
    const int bid = blockIdx.x;
    const int mh = wib >> 2, jt = wib & 3;

    if (bid == 0 && tid == 0) out[0] = 0.0f;
    for (int k = tid; k < NLAB * YDIM / 2; k += 1024)
        reinterpret_cast<unsigned*>(accz)[k] = 0u;

    // B fragments (w2) in registers: 8 k-steps for this wave's jt column-tile
    frag_ab bfr[8];
    {
        const int n = 16 * jt + (lane & 15);
        #pragma unroll
        for (int s = 0; s < 8; ++s) {
            const int k0 = 32 * s + (lane >> 4) * 8;
            #pragma unroll
            for (int i = 0; i < 8; ++i) {
                const float v = (n < YDIM) ? w2[(k0 + i) * YDIM + n] : 0.f;
                bfr[s][i] = (short)f2b(v);
            }
        }
    }
    const float4 wv = reinterpret_cast<const float4*>(w1)[lane];
    const float b1v = b1[0];
    __syncthreads();                                  // accz zeroed

    auto PREF = [&](int t, float4* r) {
        #pragma unroll
        for (int k = 0; k < 4; ++k) {
            const int rg = t * XT + 4 * wib + k;
            r[k] = (rg < NROWS)
                 ? reinterpret_cast<const float4*>(x)[(size_t)rg * 64 + lane]
                 : make_float4(0.f, 0.f, 0.f, 0.f);
        }
    };

    float4 r[4];
    PREF(bid, r);
    for (int t = bid; t < NTX; t += XBLOCKS) {
        // ---- phase 0: slab, gates, A-write, prefetch next tile ----
        if (tid < XT) {
            const int rg = t * XT + tid;
            slab[tid] = (rg < NROWS) ? labels[rg] : 0;
        }
        float p[4], g[4];
        #pragma unroll
        for (int k = 0; k < 4; ++k)
            p[k] = r[k].x * wv.x + r[k].y * wv.y + r[k].z * wv.z + r[k].w * wv.w;
        #pragma unroll
        for (int off = 32; off > 0; off >>= 1) {
            #pragma unroll
            for (int k = 0; k < 4; ++k) p[k] += __shfl_xor(p[k], off);
        }
        #pragma unroll
        for (int k = 0; k < 4; ++k)
            g[k] = 1.0f / (1.0f + __expf(-(p[k] + b1v)));

        const int row = 4 * wib;
        #pragma unroll
        for (int k = 0; k < 4; ++k) {
            const unsigned ua = (unsigned)f2b(r[k].x * g[k]) |
                                ((unsigned)f2b(r[k].y * g[k]) << 16);
            const unsigned ub = (unsigned)f2b(r[k].z * g[k]) |
                                ((unsigned)f2b(r[k].w * g[k]) << 16);
            *reinterpret_cast<uint2*>(&sA[(row + k) * ASTRIDE + lane * 4]) =
                make_uint2(ua, ub);
        }
        PREF(t + XBLOCKS, r);          // loads stay in flight across barriers
        bar_lds();                     // A + slab ready

        // ---- phase 1: MFMA, stage z-tile ----
        frag_cd c = {0.f, 0.f, 0.f, 0.f};
        #pragma unroll
        for (int s = 0; s < 8; ++s) {
            frag_ab a = *reinterpret_cast<const frag_ab*>(
                &sA[(16 * mh + (lane & 15)) * ASTRIDE + 32 * s + (lane >> 4) * 8]);
            c = __builtin_amdgcn_mfma_f32_16x16x32_bf16(a, bfr[s], c, 0, 0, 0);
        }
        const int zr = 16 * mh + (lane >> 4) * 4;
        const int zc = 16 * jt + (lane & 15);
        if (zc < YDIM) {
            zst[zr + 0][zc] = c[0]; zst[zr + 1][zc] = c[1];
            zst[zr + 2][zc] = c[2]; zst[zr + 3][zc] = c[3];
        }
        bar_lds();                     // zst ready

        // ---- phase 2: label-partitioned scatter (wave owns lbl&15==wib) ----
        {
            const int lbl_lane = slab[lane];   // row 'lane' label
            unsigned long long mask = __ballot((lbl_lane & 15) == wib);
            while (mask) {
                const int r2 = __builtin_ctzll(mask);
                mask &= mask - 1;
                const int lb = __shfl(lbl_lane, r2);
                if (lane < YDIM) {
                    const int a = lb * YDIM + lane;
                    accz[a] = f2b(b2f(accz[a]) + zst[r2][lane]);
                }
            }
        }
        bar_lds();                     // zst/slab free for next tile
    }
    __syncthreads();
    unsigned short* zp = zpart + (size_t)bid * (NLAB * YDIM);
    for (int k = tid; k < NLAB * YDIM; k += 1024) zp[k] = accz[k];
}

// ============ y stream: same label-partitioned scatter + counts ============
__global__ __launch_bounds__(1024, 4) void k_ystream(
    const float* __restrict__ y, const int* __restrict__ labels,
    unsigned short* __restrict__ ypart, int* __restrict__ gcnt)
{
    __shared__ unsigned short accy[NLAB * YDIM];   // 100,000 B
    __shared__ float yst[YT * YDIM];               //  25,600 B
    __shared__ int slab[YT];                       //     512 B
    __shared__ int cnt[NLAB];                      //   4,000 B

    const int tid = threadIdx.x, lane = tid & 63, wib = tid >> 6;
    const int bid = blockIdx.x;

    for (int k = tid; k < NLAB * YDIM / 2; k += 1024)
        reinterpret_cast<unsigned*>(accy)[k] = 0u;
    for (int k = tid; k < NLAB; k += 1024) cnt[k] = 0;
    __syncthreads();

    float v[7];
    int myl = -1;
    auto PREFY = [&](int t) {
        const size_t base = (size_t)t * YT * YDIM;
        const int n = (t < NTY) ? (min(YT, NROWS - t * YT) * YDIM) : 0;
        #pragma unroll
        for (int i = 0; i < 7; ++i) {
            const int k = tid + i * 1024;
            v[i] = (k < n) ? y[base + k] : 0.f;
        }
        if (tid < YT) {
            const int rg = t * YT + tid;
            myl = (t < NTY && rg < NROWS) ? labels[rg] : -1;
        }
    };

    PREFY(bid);
    for (int t = bid; t < NTY; t += YBLOCKS) {
        #pragma unroll
        for (int i = 0; i < 7; ++i) {
            const int k = tid + i * 1024;
            if (k < YT * YDIM) yst[k] = v[i];
        }
        if (tid < YT) {
            const bool valid = (myl >= 0);
            slab[tid] = valid ? myl : 0;
            if (valid) atomicAdd(&cnt[myl], 1);
        }
        PREFY(t + YBLOCKS);            // next tile loads in flight
        bar_lds();                     // stage + slab ready

        {
            const int l0 = slab[lane];
            const int l1 = slab[64 + lane];
            unsigned long long m0 = __ballot((l0 & 15) == wib);
            unsigned long long m1 = __ballot((l1 & 15) == wib);
            while (m0) {
                const int r = __builtin_ctzll(m0); m0 &= m0 - 1;
                const int lb = __shfl(l0, r);
                if (lane < YDIM) {
                    const int a = lb * YDIM + lane;
                    accy[a] = f2b(b2f(accy[a]) + yst[r * YDIM + lane]);
                }
            }
            while (m1) {
                const int r = __builtin_ctzll(m1); m1 &= m1 - 1;
                const int lb = __shfl(l1, r);
                if (lane < YDIM) {
                    const int a = lb * YDIM + lane;
                    accy[a] = f2b(b2f(accy[a]) + yst[(64 + r) * YDIM + lane]);
                }
            }
        }
        bar_lds();                     // yst/slab free for next stage
    }
    __syncthreads();
    unsigned short* yp = ypart + (size_t)bid * (NLAB * YDIM);
    for (int k = tid; k < NLAB * YDIM; k += 1024) yp[k] = accy[k];
    for (int k = tid; k < NLAB; k += 1024)
        if (cnt[k]) atomicAdd(&gcnt[k], cnt[k]);
}

// ============ reduce partials + double softmax + loss ============
// One block per label; 4 waves split the 256 partials; wave 0 finishes.
__global__ __launch_bounds__(256) void k_finalize(
    const unsigned short* __restrict__ zpart,
    const unsigned short* __restrict__ ypart,
    const int* __restrict__ gcnt,
    const float* __restrict__ b2, float* __restrict__ out)
{
    const int tid = threadIdx.x, lane = tid & 63, grp = tid >> 6;
    const int l = blockIdx.x;
    const bool act = lane < YDIM;
    const int off = l * YDIM + lane;

    float zs = 0.f, ys = 0.f;
    for (int b = grp; b < XBLOCKS; b += 4) {
        if (act) {
            zs += b2f(zpart[(size_t)b * (NLAB * YDIM) + off]);
            ys += b2f(ypart[(size_t)b * (NLAB * YDIM) + off]);
        }
    }
    __shared__ float rz[4][64], ry[4][64];
    rz[grp][lane] = zs; ry[grp][lane] = ys;
    __syncthreads();
    if (grp != 0) return;
    zs = rz[0][lane] + rz[1][lane] + rz[2][lane] + rz[3][lane];
    ys = ry[0][lane] + ry[1][lane] + ry[2][lane] + ry[3][lane];

    const float denom = fmaxf((float)gcnt[l], 1.0f);
    const float NEG = -3.402823466e38f;
    float logit = act ? (zs / denom + b2[lane]) : NEG;
    const float ymean = act ? (ys / denom) : 0.f;

    float m = logit;
    #pragma unroll
    for (int o = 32; o > 0; o >>= 1) m = fmaxf(m, __shfl_xor(m, o));
    float e = act ? __expf(logit - m) : 0.f;
    float s = e;
    #pragma unroll
    for (int o = 32; o > 0; o >>= 1) s += __shfl_xor(s, o);
    const float p = e / s;                 // prediction

    float pm = act ? p : NEG;              // faithful double softmax
    float m2 = pm;
    #pragma unroll
    for (int o = 32; o > 0; o >>= 1) m2 = fmaxf(m2, __shfl_xor(m2, o));
    float e2 = act ? __expf(p - m2) : 0.f;
    float s2 = e2;
    #pragma unroll
    for (int o = 32; o > 0; o >>= 1) s2 += __shfl_xor(s2, o);
    const float logp = p - m2 - __logf(s2);

    float contrib = act ? ymean * logp : 0.f;
    #pragma unroll
    for (int o = 32; o > 0; o >>= 1) contrib += __shfl_xor(contrib, o);
    if (lane == 0) atomicAdd(out, -contrib / (float)NLAB);
}

extern "C" void kernel_launch(void* const* d_in, const int* in_sizes, int n_in,
                              void* d_out, int out_size, void* d_ws, size_t ws_size,
                              hipStream_t stream) {
    const float* x      = (const float*)d_in[0];
    const int*   labels = (const int*)  d_in[1];
    const float* y      = (const float*)d_in[2];
    const float* w1     = (const float*)d_in[3];
    const float* b1     = (const float*)d_in[4];
    const float* w2     = (const float*)d_in[5];
    const float* b2     = (const float*)d_in[6];
    float* out = (float*)d_out;

    // ws: gcnt[1024] ints | zpart[256][50000] bf16 | ypart[256][50000] bf16
    int* gcnt = (int*)d_ws;
    unsigned short* zpart = (unsigned short*)((char*)d_ws + 4096);
    unsigned short* ypart = (unsigned short*)((char*)d_ws + 4096 +
                             (size_t)XBLOCKS * NLAB * YDIM * 2);

    hipMemsetAsync(gcnt, 0, NLAB * sizeof(int), stream);
    k_xstream<<<XBLOCKS, 1024, 0, stream>>>(x, labels, w1, b1, w2, zpart, out);
    k_ystream<<<YBLOCKS, 1024, 0, stream>>>(y, labels, ypart, gcnt);
    k_finalize<<<NLAB, 256, 0, stream>>>(zpart, ypart, gcnt, b2, out);
}

// Round 8
// 238.904 us; speedup vs baseline: 2.0244x; 1.1754x over previous
//
#include <hip/hip_runtime.h>
#include <math.h>

#define NROWS 500000
#define DIM 256
#define YDIM 50
#define NLAB 1000

#define XT 64
#define NTX ((NROWS + XT - 1) / XT)      // 7813 (last tile: 32 valid rows)
#define XBLOCKS 256
#define ASTRIDE 264                      // bf16 elems per A row (padded)

#define YT 128
#define NTY ((NROWS + YT - 1) / YT)      // 3907
#define YBLOCKS 256

typedef __attribute__((ext_vector_type(8))) short frag_ab;
typedef __attribute__((ext_vector_type(4))) float frag_cd;

__device__ __forceinline__ float b2f(unsigned short u) {
    return __uint_as_float(((unsigned)u) << 16);
}
__device__ __forceinline__ unsigned short f2b(float f) {   // RNE f32->bf16
    unsigned u = __float_as_uint(f);
    return (unsigned short)((u + 0x7fffu + ((u >> 16) & 1u)) >> 16);
}
// LDS-only barrier: does NOT drain vmcnt -> global prefetches stay in flight.
__device__ __forceinline__ void bar_lds() {
    asm volatile("s_waitcnt lgkmcnt(0)\n\ts_barrier" ::: "memory");
}

// ============ x stream: z = g*(x@w2); wave w owns labels (lbl&15)==w ============
// 2 barriers/tile: bar1 protects sA+slab (phase0 writes vs phase1 reads),
// bar2 protects zst (phase1 writes vs phase2 reads). accz is wave-private
// by label partition -> no barrier ever needed for it.
__global__ __launch_bounds__(1024) void k_xstream(
    const float* __restrict__ x, const int* __restrict__ labels,
    const float* __restrict__ w1, const float* __restrict__ b1,
    const float* __restrict__ w2, unsigned short* __restrict__ zpart,
    float* __restrict__ out)
{
    __shared__ unsigned short sA[XT * ASTRIDE];      // 33,792 B
    __shared__ float zst[XT][52];                    // 13,312 B
    __shared__ unsigned short accz[NLAB * YDIM];     // 100,000 B
    __shared__ int slab[2][XT];                      //    512 B

    const int tid = threadIdx.x, lane = tid & 63, wib = tid >> 6;
    const int bid = blockIdx.x;
    const int mh = wib >> 2, jt = wib & 3;

    if (bid == 0 && tid == 0) out[0] = 0.0f;
    for (int k = tid; k < NLAB * YDIM / 2; k += 1024)
        reinterpret_cast<unsigned*>(accz)[k] = 0u;

    // B fragments (w2) in registers: 8 k-steps for this wave's jt column-tile
    frag_ab bfr[8];
    {
        const int n = 16 * jt + (lane & 15);
        #pragma unroll
        for (int s = 0; s < 8; ++s) {
            const int k0 = 32 * s + (lane >> 4) * 8;
            #pragma unroll
            for (int i = 0; i < 8; ++i) {
                const float v = (n < YDIM) ? w2[(k0 + i) * YDIM + n] : 0.f;
                bfr[s][i] = (short)f2b(v);
            }
        }
    }
    const float4 wv = reinterpret_cast<const float4*>(w1)[lane];
    const float b1v = b1[0];
    __syncthreads();                                  // accz zeroed

    auto PREF = [&](int t, float4* r) {
        #pragma unroll
        for (int k = 0; k < 4; ++k) {
            const int rg = t * XT + 4 * wib + k;
            r[k] = (rg < NROWS)
                 ? reinterpret_cast<const float4*>(x)[(size_t)rg * 64 + lane]
                 : make_float4(0.f, 0.f, 0.f, 0.f);
        }
    };
    auto LLAB = [&](int t) -> int {
        const int rg = t * XT + tid;
        return (tid < XT && rg < NROWS) ? labels[rg] : 0;
    };

    auto process = [&](int t, int pft, float4* r, int& lb, int par) {
        // ---- phase 0: slab from prefetched reg, gates, A-write, prefetch ----
        if (tid < XT) slab[par][tid] = lb;
        float p[4], g[4];
        #pragma unroll
        for (int k = 0; k < 4; ++k)
            p[k] = r[k].x * wv.x + r[k].y * wv.y + r[k].z * wv.z + r[k].w * wv.w;
        #pragma unroll
        for (int off = 32; off > 0; off >>= 1) {
            #pragma unroll
            for (int k = 0; k < 4; ++k) p[k] += __shfl_xor(p[k], off);
        }
        #pragma unroll
        for (int k = 0; k < 4; ++k)
            g[k] = 1.0f / (1.0f + __expf(-(p[k] + b1v)));

        const int row = 4 * wib;
        #pragma unroll
        for (int k = 0; k < 4; ++k) {
            const unsigned ua = (unsigned)f2b(r[k].x * g[k]) |
                                ((unsigned)f2b(r[k].y * g[k]) << 16);
            const unsigned ub = (unsigned)f2b(r[k].z * g[k]) |
                                ((unsigned)f2b(r[k].w * g[k]) << 16);
            *reinterpret_cast<uint2*>(&sA[(row + k) * ASTRIDE + lane * 4]) =
                make_uint2(ua, ub);
        }
        PREF(pft, r);                  // depth-2: loads stay in flight
        lb = LLAB(pft - XBLOCKS);      // labels for the NEXT processed tile
        bar_lds();                     // bar1: sA + slab ready

        // ---- phase 1: MFMA, stage z-tile ----
        frag_cd c = {0.f, 0.f, 0.f, 0.f};
        #pragma unroll
        for (int s = 0; s < 8; ++s) {
            frag_ab a = *reinterpret_cast<const frag_ab*>(
                &sA[(16 * mh + (lane & 15)) * ASTRIDE + 32 * s + (lane >> 4) * 8]);
            c = __builtin_amdgcn_mfma_f32_16x16x32_bf16(a, bfr[s], c, 0, 0, 0);
        }
        const int zr = 16 * mh + (lane >> 4) * 4;
        const int zc = 16 * jt + (lane & 15);
        if (zc < YDIM) {
            zst[zr + 0][zc] = c[0]; zst[zr + 1][zc] = c[1];
            zst[zr + 2][zc] = c[2]; zst[zr + 3][zc] = c[3];
        }
        bar_lds();                     // bar2: zst ready

        // ---- phase 2: label-partitioned scatter (no barrier needed after) ----
        {
            const int lbl_lane = slab[par][lane];
            unsigned long long mask = __ballot((lbl_lane & 15) == wib);
            while (mask) {
                const int r2 = __builtin_ctzll(mask);
                mask &= mask - 1;
                const int lbv = __shfl(lbl_lane, r2);
                if (lane < YDIM) {
                    const int a = lbv * YDIM + lane;
                    accz[a] = f2b(b2f(accz[a]) + zst[r2][lane]);
                }
            }
        }
    };

    float4 rA[4], rB[4];
    PREF(bid, rA);
    PREF(bid + XBLOCKS, rB);
    int lbA = LLAB(bid), lbB = LLAB(bid + XBLOCKS);
    int par = 0;
    for (int t = bid; t < NTX; t += 2 * XBLOCKS) {
        process(t, t + 2 * XBLOCKS, rA, lbA, par); par ^= 1;
        if (t + XBLOCKS < NTX) {
            process(t + XBLOCKS, t + 3 * XBLOCKS, rB, lbB, par); par ^= 1;
        }
    }
    __syncthreads();
    unsigned short* zp = zpart + (size_t)bid * (NLAB * YDIM);
    for (int k = tid; k < NLAB * YDIM; k += 1024) zp[k] = accz[k];
}

// ============ y stream: 1 barrier/tile, depth-2 prefetch, + counts ============
__global__ __launch_bounds__(1024) void k_ystream(
    const float* __restrict__ y, const int* __restrict__ labels,
    unsigned short* __restrict__ ypart, int* __restrict__ gcnt)
{
    __shared__ unsigned short accy[NLAB * YDIM];   // 100,000 B
    __shared__ float yst[2][YT * YDIM];            //  51,200 B
    __shared__ int slab[2][YT];                    //   1,024 B
    __shared__ int cnt[NLAB];                      //   4,000 B

    const int tid = threadIdx.x, lane = tid & 63, wib = tid >> 6;
    const int bid = blockIdx.x;

    for (int k = tid; k < NLAB * YDIM / 2; k += 1024)
        reinterpret_cast<unsigned*>(accy)[k] = 0u;
    for (int k = tid; k < NLAB; k += 1024) cnt[k] = 0;
    __syncthreads();

    auto PREFY = [&](int t, float* v, int& myl) {
        const size_t base = (size_t)t * YT * YDIM;
        const int n = (t < NTY) ? (min(YT, NROWS - t * YT) * YDIM) : 0;
        #pragma unroll
        for (int i = 0; i < 7; ++i) {
            const int k = tid + i * 1024;
            v[i] = (k < n) ? y[base + k] : 0.f;
        }
        const int rg = t * YT + tid;
        myl = (tid < YT && t < NTY && rg < NROWS) ? labels[rg] : -1;
    };

    auto process = [&](int t, int pft, float* v, int& myl, int par) {
        #pragma unroll
        for (int i = 0; i < 7; ++i) {
            const int k = tid + i * 1024;
            if (k < YT * YDIM) yst[par][k] = v[i];
        }
        if (tid < YT) {
            const bool valid = (myl >= 0);
            slab[par][tid] = valid ? myl : 0;
            if (valid) atomicAdd(&cnt[myl], 1);
        }
        PREFY(pft, v, myl);            // depth-2: next-next tile in flight
        bar_lds();                     // yst[par] + slab[par] ready

        {
            const int l0 = slab[par][lane];
            const int l1 = slab[par][64 + lane];
            unsigned long long m0 = __ballot((l0 & 15) == wib);
            unsigned long long m1 = __ballot((l1 & 15) == wib);
            while (m0) {
                const int r = __builtin_ctzll(m0); m0 &= m0 - 1;
                const int lb = __shfl(l0, r);
                if (lane < YDIM) {
                    const int a = lb * YDIM + lane;
                    accy[a] = f2b(b2f(accy[a]) + yst[par][r * YDIM + lane]);
                }
            }
            while (m1) {
                const int r = __builtin_ctzll(m1); m1 &= m1 - 1;
                const int lb = __shfl(l1, r);
                if (lane < YDIM) {
                    const int a = lb * YDIM + lane;
                    accy[a] = f2b(b2f(accy[a]) + yst[par][(64 + r) * YDIM + lane]);
                }
            }
        }
        // no trailing barrier: next tile writes yst[par^1]; write to yst[par]
        // happens only after the NEXT bar_lds, which orders this scatter first.
    };

    float vA[7], vB[7];
    int mA, mB;
    PREFY(bid, vA, mA);
    PREFY(bid + YBLOCKS, vB, mB);
    int par = 0;
    for (int t = bid; t < NTY; t += 2 * YBLOCKS) {
        process(t, t + 2 * YBLOCKS, vA, mA, par); par ^= 1;
        if (t + YBLOCKS < NTY) {
            process(t + YBLOCKS, t + 3 * YBLOCKS, vB, mB, par); par ^= 1;
        }
    }
    __syncthreads();
    unsigned short* yp = ypart + (size_t)bid * (NLAB * YDIM);
    for (int k = tid; k < NLAB * YDIM; k += 1024) yp[k] = accy[k];
    for (int k = tid; k < NLAB; k += 1024)
        if (cnt[k]) atomicAdd(&gcnt[k], cnt[k]);
}

// ============ finalize: coalesced partial-reduce + double softmax + loss ===
// 250 blocks; block b reduces flat elements [200b, 200b+200) across the 256
// partials (400 B contiguous loads), then 4 waves each finish one label.
__global__ __launch_bounds__(256) void k_finalize(
    const unsigned short* __restrict__ zpart,
    const unsigned short* __restrict__ ypart,
    const int* __restrict__ gcnt,
    const float* __restrict__ b2, float* __restrict__ out)
{
    const int tid = threadIdx.x, lane = tid & 63, grp = tid >> 6;
    const int k0 = blockIdx.x * 200;

    float zs = 0.f, ys = 0.f;
    if (tid < 200) {
        const size_t idx = (size_t)k0 + tid;
        #pragma unroll 4
        for (int p = 0; p < XBLOCKS; ++p) {
            zs += b2f(zpart[(size_t)p * (NLAB * YDIM) + idx]);
            ys += b2f(ypart[(size_t)p * (NLAB * YDIM) + idx]);
        }
    }
    __shared__ float zl[200], yl[200];
    if (tid < 200) { zl[tid] = zs; yl[tid] = ys; }
    __syncthreads();

    const int l = blockIdx.x * 4 + grp;
    const bool act = lane < YDIM;
    const float zv = act ? zl[grp * 50 + lane] : 0.f;
    const float yv = act ? yl[grp * 50 + lane] : 0.f;

    const float denom = fmaxf((float)gcnt[l], 1.0f);
    const float NEG = -3.402823466e38f;
    float logit = act ? (zv / denom + b2[lane]) : NEG;
    const float ymean = act ? (yv / denom) : 0.f;

    float m = logit;
    #pragma unroll
    for (int o = 32; o > 0; o >>= 1) m = fmaxf(m, __shfl_xor(m, o));
    float e = act ? __expf(logit - m) : 0.f;
    float s = e;
    #pragma unroll
    for (int o = 32; o > 0; o >>= 1) s += __shfl_xor(s, o);
    const float p = e / s;                 // prediction

    float pm = act ? p : NEG;              // faithful double softmax
    float m2 = pm;
    #pragma unroll
    for (int o = 32; o > 0; o >>= 1) m2 = fmaxf(m2, __shfl_xor(m2, o));
    float e2 = act ? __expf(p - m2) : 0.f;
    float s2 = e2;
    #pragma unroll
    for (int o = 32; o > 0; o >>= 1) s2 += __shfl_xor(s2, o);
    const float logp = p - m2 - __logf(s2);

    float contrib = act ? ymean * logp : 0.f;
    #pragma unroll
    for (int o = 32; o > 0; o >>= 1) contrib += __shfl_xor(contrib, o);
    if (lane == 0) atomicAdd(out, -contrib / (float)NLAB);
}

extern "C" void kernel_launch(void* const* d_in, const int* in_sizes, int n_in,
                              void* d_out, int out_size, void* d_ws, size_t ws_size,
                              hipStream_t stream) {
    const float* x      = (const float*)d_in[0];
    const int*   labels = (const int*)  d_in[1];
    const float* y      = (const float*)d_in[2];
    const float* w1     = (const float*)d_in[3];
    const float* b1     = (const float*)d_in[4];
    const float* w2     = (const float*)d_in[5];
    const float* b2     = (const float*)d_in[6];
    float* out = (float*)d_out;

    // ws: gcnt[1024] ints | zpart[256][50000] bf16 | ypart[256][50000] bf16
    int* gcnt = (int*)d_ws;
    unsigned short* zpart = (unsigned short*)((char*)d_ws + 4096);
    unsigned short* ypart = (unsigned short*)((char*)d_ws + 4096 +
                             (size_t)XBLOCKS * NLAB * YDIM * 2);

    hipMemsetAsync(gcnt, 0, NLAB * sizeof(int), stream);
    k_xstream<<<XBLOCKS, 1024, 0, stream>>>(x, labels, w1, b1, w2, zpart, out);
    k_ystream<<<YBLOCKS, 1024, 0, stream>>>(y, labels, ypart, gcnt);
    k_finalize<<<250, 256, 0, stream>>>(zpart, ypart, gcnt, b2, out);
}

// Round 9
// 195.886 us; speedup vs baseline: 2.4690x; 1.2196x over previous
//
#include <hip/hip_runtime.h>
#include <math.h>

#define NROWS 500000
#define DIM 256
#define YDIM 50
#define NLAB 1000

#define XT 64
#define NTX ((NROWS + XT - 1) / XT)      // 7813 (last tile: 32 valid rows)
#define XBLOCKS 256
#define ASTRIDE 264                      // bf16 elems per A row (padded)
#define ZC 51                            // z' cols: 50 proj + 1 gate-dot

#define YT 128
#define NTY ((NROWS + YT - 1) / YT)      // 3907
#define YBLOCKS 256

typedef __attribute__((ext_vector_type(8))) short frag_ab;
typedef __attribute__((ext_vector_type(4))) float frag_cd;

__device__ __forceinline__ float b2f(unsigned short u) {
    return __uint_as_float(((unsigned)u) << 16);
}
__device__ __forceinline__ unsigned short f2b(float f) {   // RNE f32->bf16
    unsigned u = __float_as_uint(f);
    return (unsigned short)((u + 0x7fffu + ((u >> 16) & 1u)) >> 16);
}
// LDS-only barrier: does NOT drain vmcnt -> global prefetches stay in flight.
__device__ __forceinline__ void bar_lds() {
    asm volatile("s_waitcnt lgkmcnt(0)\n\ts_barrier" ::: "memory");
}

// ============ x stream: z' = x @ [w2|w1]; gate applied post-MFMA ============
// Wave w owns labels (lbl&15)==w -> accz never needs a barrier.
// 2 barriers/tile: bar1 = sA+slab ready, bar2 = zst ready.
__global__ __launch_bounds__(1024) void k_xstream(
    const float* __restrict__ x, const int* __restrict__ labels,
    const float* __restrict__ w1, const float* __restrict__ b1,
    const float* __restrict__ w2, unsigned short* __restrict__ zpart,
    float* __restrict__ out)
{
    __shared__ unsigned short sA[XT * ASTRIDE];      // 33,792 B
    __shared__ float zst[XT][52];                    // 13,312 B (cols 0..50)
    __shared__ unsigned short accz[NLAB * YDIM];     // 100,000 B
    __shared__ int slab[2][XT];                      //    512 B

    const int tid = threadIdx.x, lane = tid & 63, wib = tid >> 6;
    const int bid = blockIdx.x;
    const int mh = wib >> 2, jt = wib & 3;

    if (bid == 0 && tid == 0) out[0] = 0.0f;
    for (int k = tid; k < NLAB * YDIM / 2; k += 1024)
        reinterpret_cast<unsigned*>(accz)[k] = 0u;

    // B fragments: W' columns = [w2 cols 0..49 | w1 as col 50 | zeros]
    frag_ab bfr[8];
    {
        const int n = 16 * jt + (lane & 15);
        #pragma unroll
        for (int s = 0; s < 8; ++s) {
            const int k0 = 32 * s + (lane >> 4) * 8;
            #pragma unroll
            for (int i = 0; i < 8; ++i) {
                const int kk = k0 + i;
                float v = 0.f;
                if (n < YDIM)       v = w2[kk * YDIM + n];
                else if (n == YDIM) v = w1[kk];
                bfr[s][i] = (short)f2b(v);
            }
        }
    }
    const float b1v = b1[0];
    __syncthreads();                                  // accz zeroed

    auto PREF = [&](int t, float4* r) {
        #pragma unroll
        for (int k = 0; k < 4; ++k) {
            const int rg = t * XT + 4 * wib + k;
            r[k] = (rg < NROWS)
                 ? reinterpret_cast<const float4*>(x)[(size_t)rg * 64 + lane]
                 : make_float4(0.f, 0.f, 0.f, 0.f);
        }
    };
    auto LLAB = [&](int t) -> int {
        const int rg = t * XT + tid;
        return (tid < XT && rg < NROWS) ? labels[rg] : 0;
    };

    auto process = [&](int t, int pft, float4* r, int& lb, int par) {
        // ---- phase 0: slab, pack x->bf16, refill prefetch, A-write ----
        if (tid < XT) slab[par][tid] = lb;
        uint2 pk[4];
        #pragma unroll
        for (int k = 0; k < 4; ++k) {
            pk[k].x = (unsigned)f2b(r[k].x) | ((unsigned)f2b(r[k].y) << 16);
            pk[k].y = (unsigned)f2b(r[k].z) | ((unsigned)f2b(r[k].w) << 16);
        }
        PREF(pft, r);                  // depth-2: loads stay in flight
        lb = LLAB(pft);                // labels for THIS register-set's next tile
        const int row = 4 * wib;
        #pragma unroll
        for (int k = 0; k < 4; ++k)
            *reinterpret_cast<uint2*>(&sA[(row + k) * ASTRIDE + lane * 4]) = pk[k];
        bar_lds();                     // bar1: sA + slab ready

        // ---- phase 1: MFMA (gate col rides along), stage z'-tile ----
        frag_cd c = {0.f, 0.f, 0.f, 0.f};
        #pragma unroll
        for (int s = 0; s < 8; ++s) {
            frag_ab a = *reinterpret_cast<const frag_ab*>(
                &sA[(16 * mh + (lane & 15)) * ASTRIDE + 32 * s + (lane >> 4) * 8]);
            c = __builtin_amdgcn_mfma_f32_16x16x32_bf16(a, bfr[s], c, 0, 0, 0);
        }
        const int zr = 16 * mh + (lane >> 4) * 4;
        const int zc = 16 * jt + (lane & 15);
        if (zc < ZC) {
            zst[zr + 0][zc] = c[0]; zst[zr + 1][zc] = c[1];
            zst[zr + 2][zc] = c[2]; zst[zr + 3][zc] = c[3];
        }
        bar_lds();                     // bar2: zst ready

        // ---- phase 2: gated, label-partitioned scatter ----
        {
            const int lbl_lane = slab[par][lane];
            unsigned long long mask = __ballot((lbl_lane & 15) == wib);
            while (mask) {
                const int r2 = __builtin_ctzll(mask);
                mask &= mask - 1;
                const int lbv = __shfl(lbl_lane, r2);
                const float d = zst[r2][YDIM];           // broadcast read
                const float g = 1.0f / (1.0f + __expf(-(d + b1v)));
                if (lane < YDIM) {
                    const int a = lbv * YDIM + lane;
                    accz[a] = f2b(b2f(accz[a]) + g * zst[r2][lane]);
                }
            }
        }
    };

    float4 rA[4], rB[4];
    PREF(bid, rA);
    PREF(bid + XBLOCKS, rB);
    int lbA = LLAB(bid), lbB = LLAB(bid + XBLOCKS);
    int par = 0;
    for (int t = bid; t < NTX; t += 2 * XBLOCKS) {
        process(t, t + 2 * XBLOCKS, rA, lbA, par); par ^= 1;
        if (t + XBLOCKS < NTX) {
            process(t + XBLOCKS, t + 3 * XBLOCKS, rB, lbB, par); par ^= 1;
        }
    }
    __syncthreads();
    unsigned short* zp = zpart + (size_t)bid * (NLAB * YDIM);
    for (int k = tid; k < NLAB * YDIM; k += 1024) zp[k] = accz[k];
}

// ============ y stream: 1 barrier/tile, depth-2 prefetch, + counts ============
__global__ __launch_bounds__(1024) void k_ystream(
    const float* __restrict__ y, const int* __restrict__ labels,
    unsigned short* __restrict__ ypart, int* __restrict__ gcnt)
{
    __shared__ unsigned short accy[NLAB * YDIM];   // 100,000 B
    __shared__ float yst[2][YT * YDIM];            //  51,200 B
    __shared__ int slab[2][YT];                    //   1,024 B
    __shared__ int cnt[NLAB];                      //   4,000 B

    const int tid = threadIdx.x, lane = tid & 63, wib = tid >> 6;
    const int bid = blockIdx.x;

    for (int k = tid; k < NLAB * YDIM / 2; k += 1024)
        reinterpret_cast<unsigned*>(accy)[k] = 0u;
    for (int k = tid; k < NLAB; k += 1024) cnt[k] = 0;
    __syncthreads();

    auto PREFY = [&](int t, float* v, int& myl) {
        const size_t base = (size_t)t * YT * YDIM;
        const int n = (t < NTY) ? (min(YT, NROWS - t * YT) * YDIM) : 0;
        #pragma unroll
        for (int i = 0; i < 7; ++i) {
            const int k = tid + i * 1024;
            v[i] = (k < n) ? y[base + k] : 0.f;
        }
        const int rg = t * YT + tid;
        myl = (tid < YT && t < NTY && rg < NROWS) ? labels[rg] : -1;
    };

    auto process = [&](int t, int pft, float* v, int& myl, int par) {
        #pragma unroll
        for (int i = 0; i < 7; ++i) {
            const int k = tid + i * 1024;
            if (k < YT * YDIM) yst[par][k] = v[i];
        }
        if (tid < YT) {
            const bool valid = (myl >= 0);
            slab[par][tid] = valid ? myl : 0;
            if (valid) atomicAdd(&cnt[myl], 1);
        }
        PREFY(pft, v, myl);            // depth-2: next-next tile in flight
        bar_lds();                     // yst[par] + slab[par] ready

        {
            const int l0 = slab[par][lane];
            const int l1 = slab[par][64 + lane];
            unsigned long long m0 = __ballot((l0 & 15) == wib);
            unsigned long long m1 = __ballot((l1 & 15) == wib);
            while (m0) {
                const int r = __builtin_ctzll(m0); m0 &= m0 - 1;
                const int lb = __shfl(l0, r);
                if (lane < YDIM) {
                    const int a = lb * YDIM + lane;
                    accy[a] = f2b(b2f(accy[a]) + yst[par][r * YDIM + lane]);
                }
            }
            while (m1) {
                const int r = __builtin_ctzll(m1); m1 &= m1 - 1;
                const int lb = __shfl(l1, r);
                if (lane < YDIM) {
                    const int a = lb * YDIM + lane;
                    accy[a] = f2b(b2f(accy[a]) + yst[par][(64 + r) * YDIM + lane]);
                }
            }
        }
        // next tile writes yst[par^1]; yst[par] rewrite is >=1 barrier away.
    };

    float vA[7], vB[7];
    int mA, mB;
    PREFY(bid, vA, mA);
    PREFY(bid + YBLOCKS, vB, mB);
    int par = 0;
    for (int t = bid; t < NTY; t += 2 * YBLOCKS) {
        process(t, t + 2 * YBLOCKS, vA, mA, par); par ^= 1;
        if (t + YBLOCKS < NTY) {
            process(t + YBLOCKS, t + 3 * YBLOCKS, vB, mB, par); par ^= 1;
        }
    }
    __syncthreads();
    unsigned short* yp = ypart + (size_t)bid * (NLAB * YDIM);
    for (int k = tid; k < NLAB * YDIM; k += 1024) yp[k] = accy[k];
    for (int k = tid; k < NLAB; k += 1024)
        if (cnt[k]) atomicAdd(&gcnt[k], cnt[k]);
}

// ============ finalize: coalesced partial-reduce + double softmax + loss ===
__global__ __launch_bounds__(256) void k_finalize(
    const unsigned short* __restrict__ zpart,
    const unsigned short* __restrict__ ypart,
    const int* __restrict__ gcnt,
    const float* __restrict__ b2, float* __restrict__ out)
{
    const int tid = threadIdx.x, lane = tid & 63, grp = tid >> 6;
    const int k0 = blockIdx.x * 200;

    float zs = 0.f, ys = 0.f;
    if (tid < 200) {
        const size_t idx = (size_t)k0 + tid;
        #pragma unroll 4
        for (int p = 0; p < XBLOCKS; ++p) {
            zs += b2f(zpart[(size_t)p * (NLAB * YDIM) + idx]);
            ys += b2f(ypart[(size_t)p * (NLAB * YDIM) + idx]);
        }
    }
    __shared__ float zl[200], yl[200];
    if (tid < 200) { zl[tid] = zs; yl[tid] = ys; }
    __syncthreads();

    const int l = blockIdx.x * 4 + grp;
    const bool act = lane < YDIM;
    const float zv = act ? zl[grp * 50 + lane] : 0.f;
    const float yv = act ? yl[grp * 50 + lane] : 0.f;

    const float denom = fmaxf((float)gcnt[l], 1.0f);
    const float NEG = -3.402823466e38f;
    float logit = act ? (zv / denom + b2[lane]) : NEG;
    const float ymean = act ? (yv / denom) : 0.f;

    float m = logit;
    #pragma unroll
    for (int o = 32; o > 0; o >>= 1) m = fmaxf(m, __shfl_xor(m, o));
    float e = act ? __expf(logit - m) : 0.f;
    float s = e;
    #pragma unroll
    for (int o = 32; o > 0; o >>= 1) s += __shfl_xor(s, o);
    const float p = e / s;                 // prediction

    float pm = act ? p : NEG;              // faithful double softmax
    float m2 = pm;
    #pragma unroll
    for (int o = 32; o > 0; o >>= 1) m2 = fmaxf(m2, __shfl_xor(m2, o));
    float e2 = act ? __expf(p - m2) : 0.f;
    float s2 = e2;
    #pragma unroll
    for (int o = 32; o > 0; o >>= 1) s2 += __shfl_xor(s2, o);
    const float logp = p - m2 - __logf(s2);

    float contrib = act ? ymean * logp : 0.f;
    #pragma unroll
    for (int o = 32; o > 0; o >>= 1) contrib += __shfl_xor(contrib, o);
    if (lane == 0) atomicAdd(out, -contrib / (float)NLAB);
}

extern "C" void kernel_launch(void* const* d_in, const int* in_sizes, int n_in,
                              void* d_out, int out_size, void* d_ws, size_t ws_size,
                              hipStream_t stream) {
    const float* x      = (const float*)d_in[0];
    const int*   labels = (const int*)  d_in[1];
    const float* y      = (const float*)d_in[2];
    const float* w1     = (const float*)d_in[3];
    const float* b1     = (const float*)d_in[4];
    const float* w2     = (const float*)d_in[5];
    const float* b2     = (const float*)d_in[6];
    float* out = (float*)d_out;

    // ws: gcnt[1024] ints | zpart[256][50000] bf16 | ypart[256][50000] bf16
    int* gcnt = (int*)d_ws;
    unsigned short* zpart = (unsigned short*)((char*)d_ws + 4096);
    unsigned short* ypart = (unsigned short*)((char*)d_ws + 4096 +
                             (size_t)XBLOCKS * NLAB * YDIM * 2);

    hipMemsetAsync(gcnt, 0, NLAB * sizeof(int), stream);
    k_xstream<<<XBLOCKS, 1024, 0, stream>>>(x, labels, w1, b1, w2, zpart, out);
    k_ystream<<<YBLOCKS, 1024, 0, stream>>>(y, labels, ypart, gcnt);
    k_finalize<<<250, 256, 0, stream>>>(zpart, ypart, gcnt, b2, out);
}